// Round 14
// baseline (265.873 us; speedup 1.0000x reference)
//
#include <hip/hip_runtime.h>

#define NN      25000
#define TWO_N   50000
#define TT      8
#define CIN     32
#define ROWF    256      // TT*CIN elems per node row
#define COUT    64
#define FTOT    224
#define NEDGE   800000
#define NROWS   (NN * TT)            // 200000 output rows (= 12500 x 16 exactly)
#define SEGB    ((size_t)NN * ROWF)  // ushort elems per h-segment
#define BUCK    64                   // padded bucket slots per dst (P(deg>64)~1e-18)

// prep_kernel block ranges
#define PB_FEAT 6250                 // NN*ROWF/4/256
#define PB_W    56                   // 14336/256
#define PB_SCAT 3125                 // NEDGE/256

typedef __attribute__((ext_vector_type(8))) short short8v;   // bf16x8 MFMA frag
typedef __attribute__((ext_vector_type(4))) float f32x4;     // MFMA accumulator

__device__ __forceinline__ float bf2f(unsigned short u) {
    return __uint_as_float(((unsigned int)u) << 16);
}
__device__ __forceinline__ unsigned short f2bf(float f) {
    unsigned int x = __float_as_uint(f);
    return (unsigned short)((x + 0x7fffu + ((x >> 16) & 1u)) >> 16);   // RNE
}

// ---- fused prep: feat->bf16 | W->fragment-packed bf16 | bucket edge scatter ----
__global__ void prep_kernel(const float* __restrict__ feat, const float* __restrict__ W,
                            const int* __restrict__ src, const int* __restrict__ dst,
                            const float* __restrict__ ef,
                            ushort* __restrict__ FEATB, ushort* __restrict__ Wp,
                            int* __restrict__ counts, unsigned int* __restrict__ edges) {
    int bid = blockIdx.x;
    if (bid < PB_FEAT) {
        int i = bid * 256 + threadIdx.x;
        float4 v = ((const float4*)feat)[i];
        ushort4 o;
        o.x = f2bf(v.x); o.y = f2bf(v.y); o.z = f2bf(v.z); o.w = f2bf(v.w);
        ((ushort4*)FEATB)[i] = o;
    } else if (bid < PB_FEAT + PB_W) {
        int i = (bid - PB_FEAT) * 256 + threadIdx.x;
        // Wp[((a*4+ct)*64 + l)*8 + j] = W[a*32 + (l>>4)*8 + j][ct*16 + (l&15)]
        int j  = i & 7;
        int l  = (i >> 3) & 63;
        int ct = (i >> 9) & 3;
        int a  = i >> 11;
        int k   = (l >> 4) * 8 + j;
        int col = ct * 16 + (l & 15);
        Wp[i] = f2bf(W[(a * 32 + k) * COUT + col]);
    } else {
        int i = (bid - PB_FEAT - PB_W) * 256 + threadIdx.x;
        int d = dst[i];
        int c = atomicAdd(&counts[d], 1);
        if (c < BUCK) {
            unsigned int rec = ((unsigned int)f2bf(ef[i]) << 16) | (unsigned int)src[i];
            edges[(size_t)d * BUCK + c] = rec;
        }
    }
}

// ---- SpMM (bf16 storage, f32 accumulate): one wave per dst node, bucket CSR.
// At the compulsory-fetch wall: each XCD pulls the full 25.6MB operand once
// (FETCH = 8x24MB, invariant under ILP/byte changes r12->r13). Frozen.
__global__ __launch_bounds__(256) void spmm_bf_kernel(
        const int* __restrict__ counts, const unsigned int* __restrict__ edges,
        const ushort* __restrict__ hin, int wrap_in,
        const ushort* __restrict__ sub, int wrap_sub,
        float scale, ushort* __restrict__ out) {
    int wid  = (int)((blockIdx.x * blockDim.x + threadIdx.x) >> 6);
    int lane = threadIdx.x & 63;
    if (wid >= TWO_N) return;
    int cnt = counts[wid];
    if (cnt > BUCK) cnt = BUCK;
    const unsigned int* el = edges + (size_t)wid * BUCK;
    float4 a0 = make_float4(0.f, 0.f, 0.f, 0.f);
    float4 a1 = a0, a2 = a0, a3 = a0;
    int e = 0;
    for (; e + 8 <= cnt; e += 8) {
        unsigned int r0 = el[e], r1 = el[e+1], r2 = el[e+2], r3 = el[e+3];
        unsigned int r4 = el[e+4], r5 = el[e+5], r6 = el[e+6], r7 = el[e+7];
        int s0 = r0 & 0xffff, s1 = r1 & 0xffff, s2 = r2 & 0xffff, s3 = r3 & 0xffff;
        int s4 = r4 & 0xffff, s5 = r5 & 0xffff, s6 = r6 & 0xffff, s7 = r7 & 0xffff;
        if (wrap_in) {
            if (s0 >= NN) s0 -= NN;  if (s1 >= NN) s1 -= NN;
            if (s2 >= NN) s2 -= NN;  if (s3 >= NN) s3 -= NN;
            if (s4 >= NN) s4 -= NN;  if (s5 >= NN) s5 -= NN;
            if (s6 >= NN) s6 -= NN;  if (s7 >= NN) s7 -= NN;
        }
        ushort4 v0 = ((const ushort4*)(hin + (size_t)s0 * ROWF))[lane];
        ushort4 v1 = ((const ushort4*)(hin + (size_t)s1 * ROWF))[lane];
        ushort4 v2 = ((const ushort4*)(hin + (size_t)s2 * ROWF))[lane];
        ushort4 v3 = ((const ushort4*)(hin + (size_t)s3 * ROWF))[lane];
        ushort4 v4 = ((const ushort4*)(hin + (size_t)s4 * ROWF))[lane];
        ushort4 v5 = ((const ushort4*)(hin + (size_t)s5 * ROWF))[lane];
        ushort4 v6 = ((const ushort4*)(hin + (size_t)s6 * ROWF))[lane];
        ushort4 v7 = ((const ushort4*)(hin + (size_t)s7 * ROWF))[lane];
        float w0 = bf2f(r0 >> 16), w1 = bf2f(r1 >> 16);
        float w2 = bf2f(r2 >> 16), w3 = bf2f(r3 >> 16);
        float w4 = bf2f(r4 >> 16), w5 = bf2f(r5 >> 16);
        float w6 = bf2f(r6 >> 16), w7 = bf2f(r7 >> 16);
        a0.x = fmaf(w0, bf2f(v0.x), a0.x); a0.y = fmaf(w0, bf2f(v0.y), a0.y);
        a0.z = fmaf(w0, bf2f(v0.z), a0.z); a0.w = fmaf(w0, bf2f(v0.w), a0.w);
        a1.x = fmaf(w1, bf2f(v1.x), a1.x); a1.y = fmaf(w1, bf2f(v1.y), a1.y);
        a1.z = fmaf(w1, bf2f(v1.z), a1.z); a1.w = fmaf(w1, bf2f(v1.w), a1.w);
        a2.x = fmaf(w2, bf2f(v2.x), a2.x); a2.y = fmaf(w2, bf2f(v2.y), a2.y);
        a2.z = fmaf(w2, bf2f(v2.z), a2.z); a2.w = fmaf(w2, bf2f(v2.w), a2.w);
        a3.x = fmaf(w3, bf2f(v3.x), a3.x); a3.y = fmaf(w3, bf2f(v3.y), a3.y);
        a3.z = fmaf(w3, bf2f(v3.z), a3.z); a3.w = fmaf(w3, bf2f(v3.w), a3.w);
        a0.x = fmaf(w4, bf2f(v4.x), a0.x); a0.y = fmaf(w4, bf2f(v4.y), a0.y);
        a0.z = fmaf(w4, bf2f(v4.z), a0.z); a0.w = fmaf(w4, bf2f(v4.w), a0.w);
        a1.x = fmaf(w5, bf2f(v5.x), a1.x); a1.y = fmaf(w5, bf2f(v5.y), a1.y);
        a1.z = fmaf(w5, bf2f(v5.z), a1.z); a1.w = fmaf(w5, bf2f(v5.w), a1.w);
        a2.x = fmaf(w6, bf2f(v6.x), a2.x); a2.y = fmaf(w6, bf2f(v6.y), a2.y);
        a2.z = fmaf(w6, bf2f(v6.z), a2.z); a2.w = fmaf(w6, bf2f(v6.w), a2.w);
        a3.x = fmaf(w7, bf2f(v7.x), a3.x); a3.y = fmaf(w7, bf2f(v7.y), a3.y);
        a3.z = fmaf(w7, bf2f(v7.z), a3.z); a3.w = fmaf(w7, bf2f(v7.w), a3.w);
    }
    for (; e < cnt; ++e) {
        unsigned int rc = el[e];
        int s = rc & 0xffff;
        float w = bf2f(rc >> 16);
        if (wrap_in && s >= NN) s -= NN;
        ushort4 v = ((const ushort4*)(hin + (size_t)s * ROWF))[lane];
        a0.x = fmaf(w, bf2f(v.x), a0.x); a0.y = fmaf(w, bf2f(v.y), a0.y);
        a0.z = fmaf(w, bf2f(v.z), a0.z); a0.w = fmaf(w, bf2f(v.w), a0.w);
    }
    float4 acc;
    acc.x = (a0.x + a1.x) + (a2.x + a3.x);
    acc.y = (a0.y + a1.y) + (a2.y + a3.y);
    acc.z = (a0.z + a1.z) + (a2.z + a3.z);
    acc.w = (a0.w + a1.w) + (a2.w + a3.w);
    float4 r;
    if (sub != nullptr) {
        int sn = wid;
        if (wrap_sub && sn >= NN) sn -= NN;
        ushort4 sv = ((const ushort4*)(sub + (size_t)sn * ROWF))[lane];
        r.x = scale * acc.x - bf2f(sv.x);
        r.y = scale * acc.y - bf2f(sv.y);
        r.z = scale * acc.z - bf2f(sv.z);
        r.w = scale * acc.w - bf2f(sv.w);
    } else {
        r = acc;
    }
    ushort4 o;
    o.x = f2bf(r.x); o.y = f2bf(r.y); o.z = f2bf(r.z); o.w = f2bf(r.w);
    ((ushort4*)(out + (size_t)wid * ROWF))[lane] = o;
}

// ---- Output matmul on MATRIX CORES: grid-stride over 16-row tiles, no LDS.
// All 28 W-fragments hoisted into registers (statically indexed, 112 VGPR) --
// kills the 179MB of per-tile Wp re-reads. C/D map verified (m89).
__global__ __launch_bounds__(256) void out_mfma_kernel(
        const ushort* __restrict__ H, const ushort* __restrict__ Wp,
        const float* __restrict__ b, float* __restrict__ out) {
    int lane = threadIdx.x & 63;
    int wid0 = (int)((blockIdx.x * blockDim.x + threadIdx.x) >> 6);
    int nw   = (int)((gridDim.x * blockDim.x) >> 6);
    int row = lane & 15;
    int kb  = lane >> 4;

    short8v wf[28];
    #pragma unroll
    for (int i = 0; i < 28; ++i)
        wf[i] = ((const short8v*)Wp)[i * 64 + lane];
    float bv[4];
    #pragma unroll
    for (int ct = 0; ct < 4; ++ct) bv[ct] = b[ct * 16 + row];

    for (int tile = wid0; tile < NROWS / 16; tile += nw) {
        int rbase = tile * 16;
        f32x4 acc[4];
        #pragma unroll
        for (int ct = 0; ct < 4; ++ct) {
            acc[ct][0] = bv[ct]; acc[ct][1] = bv[ct];
            acc[ct][2] = bv[ct]; acc[ct][3] = bv[ct];
        }
        const ushort* ha = H + (size_t)(rbase + row) * CIN + kb * 8;
        #pragma unroll
        for (int a = 0; a < 7; ++a) {
            short8v af = *(const short8v*)(ha + (size_t)a * SEGB);
            acc[0] = __builtin_amdgcn_mfma_f32_16x16x32_bf16(af, wf[a * 4 + 0], acc[0], 0, 0, 0);
            acc[1] = __builtin_amdgcn_mfma_f32_16x16x32_bf16(af, wf[a * 4 + 1], acc[1], 0, 0, 0);
            acc[2] = __builtin_amdgcn_mfma_f32_16x16x32_bf16(af, wf[a * 4 + 2], acc[2], 0, 0, 0);
            acc[3] = __builtin_amdgcn_mfma_f32_16x16x32_bf16(af, wf[a * 4 + 3], acc[3], 0, 0, 0);
        }
        int orow = rbase + kb * 4;
        #pragma unroll
        for (int ct = 0; ct < 4; ++ct) {
            int col = ct * 16 + row;
            #pragma unroll
            for (int r = 0; r < 4; ++r)
                out[(size_t)(orow + r) * COUT + col] = acc[ct][r];
        }
    }
}

extern "C" void kernel_launch(void* const* d_in, const int* in_sizes, int n_in,
                              void* d_out, int out_size, void* d_ws, size_t ws_size,
                              hipStream_t stream) {
    const float* feat = (const float*)d_in[0];
    const float* ef   = (const float*)d_in[1];
    const float* W    = (const float*)d_in[2];
    const float* b    = (const float*)d_in[3];
    const int*   src  = (const int*)d_in[4];
    const int*   dst  = (const int*)d_in[5];
    float* out = (float*)d_out;

    // Workspace: [FEATB][X1B][X2B][X3B] bf16 (89.6 MB), [Wp], [counts], [edges 12.8 MB]
    ushort* FEATB = (ushort*)d_ws;
    ushort* X1B = FEATB + SEGB;
    ushort* X2B = X1B + (size_t)TWO_N * ROWF;
    ushort* X3B = X2B + (size_t)TWO_N * ROWF;
    ushort* Wp  = X3B + (size_t)TWO_N * ROWF;
    int* counts = (int*)(Wp + 7 * 4 * 64 * 8);
    unsigned int* edges = (unsigned int*)(counts + TWO_N + 64);

    hipMemsetAsync(counts, 0, TWO_N * sizeof(int), stream);
    prep_kernel<<<PB_FEAT + PB_W + PB_SCAT, 256, 0, stream>>>(feat, W, src, dst, ef,
                                                              FEATB, Wp, counts, edges);

    int spmm_grid = (TWO_N + 3) / 4;
    spmm_bf_kernel<<<spmm_grid, 256, 0, stream>>>(counts, edges,
                                                  FEATB, 1, nullptr, 0, 1.0f, X1B);
    spmm_bf_kernel<<<spmm_grid, 256, 0, stream>>>(counts, edges,
                                                  X1B, 0, FEATB, 1, 2.0f, X2B);
    spmm_bf_kernel<<<spmm_grid, 256, 0, stream>>>(counts, edges,
                                                  X2B, 0, X1B, 0, 2.0f, X3B);

    // Output projection: MFMA, grid-stride, 512 blocks x 4 waves
    out_mfma_kernel<<<512, 256, 0, stream>>>(FEATB, Wp, b, out);
}

// Round 15
// 261.096 us; speedup vs baseline: 1.0183x; 1.0183x over previous
//
#include <hip/hip_runtime.h>

#define NN      25000
#define TWO_N   50000
#define TT      8
#define CIN     32
#define ROWF    256      // TT*CIN elems per node row
#define COUT    64
#define FTOT    224
#define NEDGE   800000
#define NROWS   (NN * TT)            // 200000 output rows (= 12500 x 16 exactly)
#define SEGB    ((size_t)NN * ROWF)  // ushort elems per h-segment
#define BUCK    64                   // padded bucket slots per dst (P(deg>64)~1e-18)

typedef __attribute__((ext_vector_type(8))) short short8v;   // bf16x8 MFMA frag
typedef __attribute__((ext_vector_type(4))) float f32x4;     // MFMA accumulator

__device__ __forceinline__ float bf2f(unsigned short u) {
    return __uint_as_float(((unsigned int)u) << 16);
}
__device__ __forceinline__ unsigned short f2bf(float f) {
    unsigned int x = __float_as_uint(f);
    return (unsigned short)((x + 0x7fffu + ((x >> 16) & 1u)) >> 16);   // RNE
}

// ---- bucket scatter (separate kernel — fusion with streaming conv regressed r14) ----
__global__ void scatter_kernel(const int* __restrict__ src, const int* __restrict__ dst,
                               const float* __restrict__ ef,
                               int* __restrict__ counts, unsigned int* __restrict__ edges) {
    int i = blockIdx.x * blockDim.x + threadIdx.x;
    if (i < NEDGE) {
        int d = dst[i];
        int c = atomicAdd(&counts[d], 1);
        if (c < BUCK) {
            unsigned int rec = ((unsigned int)f2bf(ef[i]) << 16) | (unsigned int)src[i];
            edges[(size_t)d * BUCK + c] = rec;
        }
    }
}

// feat (f32) -> FEATB (bf16)
__global__ void feat2bf_kernel(const float* __restrict__ feat, ushort* __restrict__ dstp) {
    int i = blockIdx.x * blockDim.x + threadIdx.x;
    float4 v = ((const float4*)feat)[i];
    ushort4 o;
    o.x = f2bf(v.x); o.y = f2bf(v.y); o.z = f2bf(v.z); o.w = f2bf(v.w);
    ((ushort4*)dstp)[i] = o;
}

// W (f32 [224][64]) -> bf16 in MFMA B-fragment order
__global__ void packW_kernel(const float* __restrict__ W, ushort* __restrict__ Wp) {
    int i = blockIdx.x * blockDim.x + threadIdx.x;
    if (i >= 7 * 4 * 64 * 8) return;
    int j  = i & 7;
    int l  = (i >> 3) & 63;
    int ct = (i >> 9) & 3;
    int a  = i >> 11;
    int k   = (l >> 4) * 8 + j;
    int col = ct * 16 + (l & 15);
    Wp[i] = f2bf(W[(a * 32 + k) * COUT + col]);
}

// ---- SpMM (bf16 storage, f32 accumulate): one wave per dst node, bucket CSR.
// 16-deep gather pipeline: all of a node's gathers issued before any FMA
// (probe of the latency-vs-fabric-wall question; r13's 8-deep was null).
__global__ __launch_bounds__(256) void spmm_bf_kernel(
        const int* __restrict__ counts, const unsigned int* __restrict__ edges,
        const ushort* __restrict__ hin, int wrap_in,
        const ushort* __restrict__ sub, int wrap_sub,
        float scale, ushort* __restrict__ out) {
    int wid  = (int)((blockIdx.x * blockDim.x + threadIdx.x) >> 6);
    int lane = threadIdx.x & 63;
    if (wid >= TWO_N) return;
    int cnt = counts[wid];
    if (cnt > BUCK) cnt = BUCK;
    const unsigned int* el = edges + (size_t)wid * BUCK;
    float4 a0 = make_float4(0.f, 0.f, 0.f, 0.f);
    float4 a1 = a0, a2 = a0, a3 = a0;
    int e = 0;
    for (; e + 16 <= cnt; e += 16) {
        ushort4 v[16];
        float   w[16];
        #pragma unroll
        for (int j = 0; j < 16; ++j) {
            unsigned int rc = el[e + j];
            int s = (int)(rc & 0xffffu);
            if (wrap_in && s >= NN) s -= NN;
            v[j] = ((const ushort4*)(hin + (size_t)s * ROWF))[lane];
            w[j] = bf2f((unsigned short)(rc >> 16));
        }
        #pragma unroll
        for (int j = 0; j < 16; j += 4) {
            a0.x = fmaf(w[j],   bf2f(v[j].x),   a0.x); a0.y = fmaf(w[j],   bf2f(v[j].y),   a0.y);
            a0.z = fmaf(w[j],   bf2f(v[j].z),   a0.z); a0.w = fmaf(w[j],   bf2f(v[j].w),   a0.w);
            a1.x = fmaf(w[j+1], bf2f(v[j+1].x), a1.x); a1.y = fmaf(w[j+1], bf2f(v[j+1].y), a1.y);
            a1.z = fmaf(w[j+1], bf2f(v[j+1].z), a1.z); a1.w = fmaf(w[j+1], bf2f(v[j+1].w), a1.w);
            a2.x = fmaf(w[j+2], bf2f(v[j+2].x), a2.x); a2.y = fmaf(w[j+2], bf2f(v[j+2].y), a2.y);
            a2.z = fmaf(w[j+2], bf2f(v[j+2].z), a2.z); a2.w = fmaf(w[j+2], bf2f(v[j+2].w), a2.w);
            a3.x = fmaf(w[j+3], bf2f(v[j+3].x), a3.x); a3.y = fmaf(w[j+3], bf2f(v[j+3].y), a3.y);
            a3.z = fmaf(w[j+3], bf2f(v[j+3].z), a3.z); a3.w = fmaf(w[j+3], bf2f(v[j+3].w), a3.w);
        }
    }
    for (; e + 4 <= cnt; e += 4) {
        ushort4 v[4];
        float   w[4];
        #pragma unroll
        for (int j = 0; j < 4; ++j) {
            unsigned int rc = el[e + j];
            int s = (int)(rc & 0xffffu);
            if (wrap_in && s >= NN) s -= NN;
            v[j] = ((const ushort4*)(hin + (size_t)s * ROWF))[lane];
            w[j] = bf2f((unsigned short)(rc >> 16));
        }
        a0.x = fmaf(w[0], bf2f(v[0].x), a0.x); a0.y = fmaf(w[0], bf2f(v[0].y), a0.y);
        a0.z = fmaf(w[0], bf2f(v[0].z), a0.z); a0.w = fmaf(w[0], bf2f(v[0].w), a0.w);
        a1.x = fmaf(w[1], bf2f(v[1].x), a1.x); a1.y = fmaf(w[1], bf2f(v[1].y), a1.y);
        a1.z = fmaf(w[1], bf2f(v[1].z), a1.z); a1.w = fmaf(w[1], bf2f(v[1].w), a1.w);
        a2.x = fmaf(w[2], bf2f(v[2].x), a2.x); a2.y = fmaf(w[2], bf2f(v[2].y), a2.y);
        a2.z = fmaf(w[2], bf2f(v[2].z), a2.z); a2.w = fmaf(w[2], bf2f(v[2].w), a2.w);
        a3.x = fmaf(w[3], bf2f(v[3].x), a3.x); a3.y = fmaf(w[3], bf2f(v[3].y), a3.y);
        a3.z = fmaf(w[3], bf2f(v[3].z), a3.z); a3.w = fmaf(w[3], bf2f(v[3].w), a3.w);
    }
    for (; e < cnt; ++e) {
        unsigned int rc = el[e];
        int s = (int)(rc & 0xffffu);
        float w = bf2f((unsigned short)(rc >> 16));
        if (wrap_in && s >= NN) s -= NN;
        ushort4 v = ((const ushort4*)(hin + (size_t)s * ROWF))[lane];
        a0.x = fmaf(w, bf2f(v.x), a0.x); a0.y = fmaf(w, bf2f(v.y), a0.y);
        a0.z = fmaf(w, bf2f(v.z), a0.z); a0.w = fmaf(w, bf2f(v.w), a0.w);
    }
    float4 acc;
    acc.x = (a0.x + a1.x) + (a2.x + a3.x);
    acc.y = (a0.y + a1.y) + (a2.y + a3.y);
    acc.z = (a0.z + a1.z) + (a2.z + a3.z);
    acc.w = (a0.w + a1.w) + (a2.w + a3.w);
    float4 r;
    if (sub != nullptr) {
        int sn = wid;
        if (wrap_sub && sn >= NN) sn -= NN;
        ushort4 sv = ((const ushort4*)(sub + (size_t)sn * ROWF))[lane];
        r.x = scale * acc.x - bf2f(sv.x);
        r.y = scale * acc.y - bf2f(sv.y);
        r.z = scale * acc.z - bf2f(sv.z);
        r.w = scale * acc.w - bf2f(sv.w);
    } else {
        r = acc;
    }
    ushort4 o;
    o.x = f2bf(r.x); o.y = f2bf(r.y); o.z = f2bf(r.z); o.w = f2bf(r.w);
    ((ushort4*)(out + (size_t)wid * ROWF))[lane] = o;
}

// ---- Output matmul on MATRIX CORES: grid-stride over 16-row tiles, no LDS,
// all 28 W-fragments + bias in registers (statically indexed). ----
__global__ __launch_bounds__(256) void out_mfma_kernel(
        const ushort* __restrict__ H, const ushort* __restrict__ Wp,
        const float* __restrict__ b, float* __restrict__ out) {
    int lane = threadIdx.x & 63;
    int wid0 = (int)((blockIdx.x * blockDim.x + threadIdx.x) >> 6);
    int nw   = (int)((gridDim.x * blockDim.x) >> 6);
    int row = lane & 15;
    int kb  = lane >> 4;

    short8v wf[28];
    #pragma unroll
    for (int i = 0; i < 28; ++i)
        wf[i] = ((const short8v*)Wp)[i * 64 + lane];
    float bv[4];
    #pragma unroll
    for (int ct = 0; ct < 4; ++ct) bv[ct] = b[ct * 16 + row];

    for (int tile = wid0; tile < NROWS / 16; tile += nw) {
        int rbase = tile * 16;
        f32x4 acc[4];
        #pragma unroll
        for (int ct = 0; ct < 4; ++ct) {
            acc[ct][0] = bv[ct]; acc[ct][1] = bv[ct];
            acc[ct][2] = bv[ct]; acc[ct][3] = bv[ct];
        }
        const ushort* ha = H + (size_t)(rbase + row) * CIN + kb * 8;
        #pragma unroll
        for (int a = 0; a < 7; ++a) {
            short8v af = *(const short8v*)(ha + (size_t)a * SEGB);
            acc[0] = __builtin_amdgcn_mfma_f32_16x16x32_bf16(af, wf[a * 4 + 0], acc[0], 0, 0, 0);
            acc[1] = __builtin_amdgcn_mfma_f32_16x16x32_bf16(af, wf[a * 4 + 1], acc[1], 0, 0, 0);
            acc[2] = __builtin_amdgcn_mfma_f32_16x16x32_bf16(af, wf[a * 4 + 2], acc[2], 0, 0, 0);
            acc[3] = __builtin_amdgcn_mfma_f32_16x16x32_bf16(af, wf[a * 4 + 3], acc[3], 0, 0, 0);
        }
        int orow = rbase + kb * 4;
        #pragma unroll
        for (int ct = 0; ct < 4; ++ct) {
            int col = ct * 16 + row;
            #pragma unroll
            for (int r = 0; r < 4; ++r)
                out[(size_t)(orow + r) * COUT + col] = acc[ct][r];
        }
    }
}

extern "C" void kernel_launch(void* const* d_in, const int* in_sizes, int n_in,
                              void* d_out, int out_size, void* d_ws, size_t ws_size,
                              hipStream_t stream) {
    const float* feat = (const float*)d_in[0];
    const float* ef   = (const float*)d_in[1];
    const float* W    = (const float*)d_in[2];
    const float* b    = (const float*)d_in[3];
    const int*   src  = (const int*)d_in[4];
    const int*   dst  = (const int*)d_in[5];
    float* out = (float*)d_out;

    // Workspace: [FEATB][X1B][X2B][X3B] bf16 (89.6 MB), [Wp], [counts], [edges 12.8 MB]
    ushort* FEATB = (ushort*)d_ws;
    ushort* X1B = FEATB + SEGB;
    ushort* X2B = X1B + (size_t)TWO_N * ROWF;
    ushort* X3B = X2B + (size_t)TWO_N * ROWF;
    ushort* Wp  = X3B + (size_t)TWO_N * ROWF;
    int* counts = (int*)(Wp + 7 * 4 * 64 * 8);
    unsigned int* edges = (unsigned int*)(counts + TWO_N + 64);

    feat2bf_kernel<<<(NN * ROWF / 4) / 256, 256, 0, stream>>>(feat, FEATB);
    packW_kernel<<<56, 256, 0, stream>>>(W, Wp);

    hipMemsetAsync(counts, 0, TWO_N * sizeof(int), stream);
    scatter_kernel<<<(NEDGE + 255) / 256, 256, 0, stream>>>(src, dst, ef, counts, edges);

    int spmm_grid = (TWO_N + 3) / 4;
    spmm_bf_kernel<<<spmm_grid, 256, 0, stream>>>(counts, edges,
                                                  FEATB, 1, nullptr, 0, 1.0f, X1B);
    spmm_bf_kernel<<<spmm_grid, 256, 0, stream>>>(counts, edges,
                                                  X1B, 0, FEATB, 1, 2.0f, X2B);
    spmm_bf_kernel<<<spmm_grid, 256, 0, stream>>>(counts, edges,
                                                  X2B, 0, X1B, 0, 2.0f, X3B);

    // Output projection: MFMA, grid-stride, 512 blocks x 4 waves
    out_mfma_kernel<<<512, 256, 0, stream>>>(FEATB, Wp, b, out);
}